// Round 6
// baseline (472.284 us; speedup 1.0000x reference)
//
#include <hip/hip_runtime.h>

// DGMNet fused kernel for MI355X (gfx950) — round 6.
// R5 landed spill-free (VGPR 64, WRITE 16MB) and issue-bound (VALU 66.7% +
// MFMA 19.6% ~ 86% of issue slots). R6 cuts dynamic instructions:
//  - u-projections pre-biased and kept in fp32 regs; each layer GEMM inits
//    its accumulator with u (MFMA C-operand) -> no ub LDS, no u pack/unpack,
//    no per-gate bias adds.
//  - sreg/tp/gp kept fp32 (no pack/unpack round-trips).
//  - LDS pinned at exactly 64KB (16KB real + 48KB volatile-kept pad): the RA
//    targets the LDS-implied occupancy tier (R2-R5 evidence), 64KB/512thr ->
//    4 waves/EU -> 128-reg budget, matching ~110-130 live regs.
//  - prep kernel rewritten with coalesced float4 reads.

typedef __attribute__((ext_vector_type(8))) short bf16x8;
typedef __attribute__((ext_vector_type(4))) float f32x4;
typedef __attribute__((ext_vector_type(4))) unsigned int u32x4;
typedef __attribute__((ext_vector_type(2))) unsigned int u32x2;

#define HID 128
#define XD 100
#define BROWS 32
#define NMAT 9
#define MATS 16384   // ushorts per 128x128 matrix

// ---------- bf16 helpers (RNE) ----------
__device__ __forceinline__ unsigned short f2bf(float f) {
    unsigned u = __float_as_uint(f);
    return (unsigned short)((u + 0x7FFFu + ((u >> 16) & 1u)) >> 16);
}
__device__ __forceinline__ unsigned pack2(float lo, float hi) {
    unsigned ul = __float_as_uint(lo), uh = __float_as_uint(hi);
    unsigned bl = (ul + 0x7FFFu + ((ul >> 16) & 1u)) >> 16;
    unsigned bh = (uh + 0x7FFFu + ((uh >> 16) & 1u)) & 0xFFFF0000u;
    return bl | bh;
}

__device__ __forceinline__ float fast_tanh(float x) {
    float e = __expf(2.0f * x);
    return 1.0f - 2.0f * __builtin_amdgcn_rcpf(e + 1.0f);
}
__device__ __forceinline__ float one_m_tanh(float x) {   // 1 - tanh(x)
    float e = __expf(2.0f * x);
    return 2.0f * __builtin_amdgcn_rcpf(e + 1.0f);
}

// ---------- prep: fp32 [K][128] -> bf16 fragment order (coalesced reads) ----
// mats: 0 Sw 1 Uz 2 Ug 3 Ur 4 Uh (K=101, pad to 128) | 5 Wsz 6 Wsg 7 Wsr 8 Wsh
// frag layout: ((ks*8+nt)*64+lane)*8+b <-> W[k=ks*32+(lane>>4)*8+b][n=nt*16+(lane&15)]
// One thread per (mat, k, n-quad): float4 coalesced read, 4 scattered b16 writes.
__global__ void prep_kernel(const float* __restrict__ Sw, const float* __restrict__ Uz,
                            const float* __restrict__ Ug, const float* __restrict__ Ur,
                            const float* __restrict__ Uh, const float* __restrict__ Wsz,
                            const float* __restrict__ Wsg, const float* __restrict__ Wsr,
                            const float* __restrict__ Wsh, unsigned short* __restrict__ out) {
    int g = blockIdx.x * blockDim.x + threadIdx.x;
    if (g >= NMAT * 4096) return;           // 128 k x 32 n-quads per matrix
    int m = g >> 12, r = g & 4095;
    int k = r >> 5, n4 = (r & 31) * 4;
    const float* src; int kmax;
    switch (m) {
        case 0: src = Sw;  kmax = 101; break;
        case 1: src = Uz;  kmax = 101; break;
        case 2: src = Ug;  kmax = 101; break;
        case 3: src = Ur;  kmax = 101; break;
        case 4: src = Uh;  kmax = 101; break;
        case 5: src = Wsz; kmax = 128; break;
        case 6: src = Wsg; kmax = 128; break;
        case 7: src = Wsr; kmax = 128; break;
        default: src = Wsh; kmax = 128; break;
    }
    f32x4 v = (f32x4){0.f, 0.f, 0.f, 0.f};
    if (k < kmax) v = *(const f32x4*)(src + k * HID + n4);
    int ks = k >> 5, b = k & 7, lq = ((k >> 3) & 3) << 4;
    int nt = n4 >> 4;                       // same for all 4 (n4 is 4-aligned)
    size_t mb = (size_t)m * MATS;
    #pragma unroll
    for (int i = 0; i < 4; ++i) {
        int lane = lq | ((n4 + i) & 15);
        out[mb + (size_t)((ks * 8 + nt) * 64 + lane) * 8 + b] = f2bf(v[i]);
    }
}

// ---------- GEMM: A (LDS, frag order, 32 rows x 128 k) x B (regs, 1 n-tile) ----------
// acc must be pre-initialized by the caller (C-operand carries u/bias).
__device__ __forceinline__ void gemm32(const unsigned short* __restrict__ A,
                                       const bf16x8 (&B)[4], int lane,
                                       f32x4 (&acc)[2]) {
    #pragma unroll
    for (int ks = 0; ks < 4; ++ks) {
        #pragma unroll
        for (int mt = 0; mt < 2; ++mt) {
            bf16x8 a = *(const bf16x8*)(A + mt * 2048 + ks * 512 + lane * 8);
            acc[mt] = __builtin_amdgcn_mfma_f32_16x16x32_bf16(a, B[ks], acc[mt], 0, 0, 0);
        }
    }
}

__device__ __forceinline__ void loadB(const unsigned short* __restrict__ wbuf, int mat,
                                      int nt, int lane, bf16x8 (&B)[4]) {
    #pragma unroll
    for (int ks = 0; ks < 4; ++ks)
        B[ks] = *(const bf16x8*)(wbuf + (size_t)mat * MATS +
                                 ((size_t)((ks * 8 + nt) * 64 + lane)) * 8);
}

// ---------- main ----------
__global__ __launch_bounds__(512, 4)
void dgm_main(const float* __restrict__ x, const float* __restrict__ tptr,
              const unsigned short* __restrict__ wbuf,
              const float* __restrict__ Sw_b, const float* __restrict__ Uz_b,
              const float* __restrict__ Ug_b, const float* __restrict__ Ur_b,
              const float* __restrict__ Uh_b,
              const float* __restrict__ Wsz_b, const float* __restrict__ Wsg_b,
              const float* __restrict__ Wsr_b, const float* __restrict__ Wsh_b,
              const float* __restrict__ Wf_w, const float* __restrict__ Wf_b,
              const int* __restrict__ nlayers, float* __restrict__ y) {
    __shared__ unsigned short xtb[2 * 2048];    // 8KB: xt, later S*R (A-frag order)
    __shared__ unsigned short sb[2 * 2048];     // 8KB: S (A-frag order)
    __shared__ unsigned short ldspad[24576];    // 48KB pad -> 64KB total: pins the
                                                // LDS tier at 2 blocks/CU = 4 w/EU
                                                // so the RA budget is 128 regs.

    const int tid = threadIdx.x;
    const int wv = tid >> 6, lane = tid & 63;
    const int quad = lane >> 4, l15 = lane & 15;
    const int blk = blockIdx.x;
    const int lcount = nlayers[0] - 1;
    const int nt = wv;                       // one 16-col n-tile per wave

    // keep ldspad allocated: volatile store in a runtime-false branch (DSE-proof)
    if (lcount == 0x7fffffff) ((volatile unsigned short*)ldspad)[tid] = 1;

    const int col = nt * 16 + l15;
    const int sc = (col >> 5) * 512 + ((col >> 3) & 3) * 128 + (col & 7) + quad * 32;

    // ---- zero the k>=96 pad frags of xtb (frag ks==3), then fill xt ----
    {
        int mt = tid >> 8;
        ((unsigned*)xtb)[mt * 1024 + 768 + (tid & 255)] = 0u;
    }
    __syncthreads();

    {
        const float* xsrc = x + (size_t)blk * BROWS * XD;
        for (int i = tid; i < BROWS * (XD / 4); i += 512) {     // 800 float4s
            int row = i / 25, c4 = i % 25, k0 = c4 * 4;
            f32x4 v = *(const f32x4*)(xsrc + row * XD + k0);
            int idx = (row >> 4) * 2048 + (k0 >> 5) * 512 + ((k0 >> 3) & 3) * 128 +
                      (row & 15) * 8 + (k0 & 7);
            *(u32x2*)(xtb + idx) = (u32x2){pack2(v[0], v[1]), pack2(v[2], v[3])};
        }
        if (tid < BROWS) {                                      // t column, k=100
            int idx = (tid >> 4) * 2048 + 3 * 512 + (tid & 15) * 8 + 4;
            xtb[idx] = f2bf(tptr[(size_t)blk * BROWS + tid]);
        }
    }
    __syncthreads();

    f32x4 acc[2];
    f32x4 sreg4[2];       // S (fp32, C-layout)
    f32x4 u4[4][2];       // pre-biased projections: 0 uz, 1 ug, 2 ur, 3 uh (fp32)
    bf16x8 Bcur[4], Bnxt[4];

    // ---- projection phase: Sw, then Uz/Ug/Ur/Uh (bias folded into C-init) ----
    loadB(wbuf, 0, nt, lane, Bcur);
    {
        float bv = Sw_b[col];
        loadB(wbuf, 1, nt, lane, Bnxt);   // prefetch Uz
        acc[0] = (f32x4){bv, bv, bv, bv};
        acc[1] = acc[0];
        gemm32(xtb, Bcur, lane, acc);
        #pragma unroll
        for (int mt = 0; mt < 2; ++mt) {
            f32x4 s;
            s[0] = fast_tanh(acc[mt][0]);
            s[1] = fast_tanh(acc[mt][1]);
            s[2] = fast_tanh(acc[mt][2]);
            s[3] = fast_tanh(acc[mt][3]);
            sreg4[mt] = s;
            unsigned p01 = pack2(s[0], s[1]), p23 = pack2(s[2], s[3]);
            int base = mt * 2048 + sc;
            sb[base + 0]  = (unsigned short)p01;
            sb[base + 8]  = (unsigned short)(p01 >> 16);
            sb[base + 16] = (unsigned short)p23;
            sb[base + 24] = (unsigned short)(p23 >> 16);
        }
    }
    {
        const float* ubias[4] = {Uz_b, Ug_b, Ur_b, Uh_b};
        #pragma unroll
        for (int mi = 0; mi < 4; ++mi) {
            #pragma unroll
            for (int ks = 0; ks < 4; ++ks)
                Bcur[ks] = Bnxt[ks];
            if (mi < 3) loadB(wbuf, mi + 2, nt, lane, Bnxt);
            float bv = ubias[mi][col];
            acc[0] = (f32x4){bv, bv, bv, bv};
            acc[1] = acc[0];
            gemm32(xtb, Bcur, lane, acc);    // acc = xt@U + b  (pre-biased u)
            u4[mi][0] = acc[0];
            u4[mi][1] = acc[1];
        }
    }
    __syncthreads();   // S1 visible to all waves

    // ---- persistent layer weights (B-fragments, this wave's n-tile) ----
    bf16x8 Wz[4], Wg[4], Wr[4], Wh[4];
    loadB(wbuf, 5, nt, lane, Wz);
    loadB(wbuf, 6, nt, lane, Wg);
    loadB(wbuf, 7, nt, lane, Wr);
    loadB(wbuf, 8, nt, lane, Wh);

    f32x4 tp4[2];   // Z*S (fp32)
    f32x4 gp4[2];   // 1-G (fp32)

    // ---- recurrent layers: R -> Z -> G -> H ----
    for (int l = 0; l < lcount; ++l) {
        // R = tanh(ur + S@Wsr); write S*R into xtb
        acc[0] = u4[2][0]; acc[1] = u4[2][1];
        gemm32(sb, Wr, lane, acc);
        #pragma unroll
        for (int mt = 0; mt < 2; ++mt) {
            float q0 = sreg4[mt][0] * fast_tanh(acc[mt][0]);
            float q1 = sreg4[mt][1] * fast_tanh(acc[mt][1]);
            float q2 = sreg4[mt][2] * fast_tanh(acc[mt][2]);
            float q3 = sreg4[mt][3] * fast_tanh(acc[mt][3]);
            unsigned q01 = pack2(q0, q1), q23 = pack2(q2, q3);
            int base = mt * 2048 + sc;
            xtb[base + 0]  = (unsigned short)q01;
            xtb[base + 8]  = (unsigned short)(q01 >> 16);
            xtb[base + 16] = (unsigned short)q23;
            xtb[base + 24] = (unsigned short)(q23 >> 16);
        }
        __syncthreads();   // S*R visible

        // Z = tanh(uz + S@Wsz); tp = Z*S
        acc[0] = u4[0][0]; acc[1] = u4[0][1];
        gemm32(sb, Wz, lane, acc);
        #pragma unroll
        for (int mt = 0; mt < 2; ++mt) {
            tp4[mt][0] = fast_tanh(acc[mt][0]) * sreg4[mt][0];
            tp4[mt][1] = fast_tanh(acc[mt][1]) * sreg4[mt][1];
            tp4[mt][2] = fast_tanh(acc[mt][2]) * sreg4[mt][2];
            tp4[mt][3] = fast_tanh(acc[mt][3]) * sreg4[mt][3];
        }

        // 1-G = 2/(exp(2*(ug + S@Wsg))+1)
        acc[0] = u4[1][0]; acc[1] = u4[1][1];
        gemm32(sb, Wg, lane, acc);
        #pragma unroll
        for (int mt = 0; mt < 2; ++mt) {
            gp4[mt][0] = one_m_tanh(acc[mt][0]);
            gp4[mt][1] = one_m_tanh(acc[mt][1]);
            gp4[mt][2] = one_m_tanh(acc[mt][2]);
            gp4[mt][3] = one_m_tanh(acc[mt][3]);
        }

        // H = uh + (S*R)@Wsh ; out = (1-G)*H + Z*S
        acc[0] = u4[3][0]; acc[1] = u4[3][1];
        gemm32(xtb, Wh, lane, acc);
        __syncthreads();   // all waves done reading sb/xtb for this layer
        bool lastl = (l == lcount - 1);
        #pragma unroll
        for (int mt = 0; mt < 2; ++mt) {
            f32x4 o;
            o[0] = gp4[mt][0] * acc[mt][0] + tp4[mt][0];
            o[1] = gp4[mt][1] * acc[mt][1] + tp4[mt][1];
            o[2] = gp4[mt][2] * acc[mt][2] + tp4[mt][2];
            o[3] = gp4[mt][3] * acc[mt][3] + tp4[mt][3];
            sreg4[mt] = o;
            if (!lastl) {
                unsigned p01 = pack2(o[0], o[1]), p23 = pack2(o[2], o[3]);
                int base = mt * 2048 + sc;
                sb[base + 0]  = (unsigned short)p01;
                sb[base + 8]  = (unsigned short)(p01 >> 16);
                sb[base + 16] = (unsigned short)p23;
                sb[base + 24] = (unsigned short)(p23 >> 16);
            }
        }
        if (!lastl) __syncthreads();   // new S visible for next layer
    }

    // ---- final: y = out @ Wf + Wf_b (per-wave partials, combine via LDS) ----
    float* yp = (float*)xtb;   // safe: barrier after H-gemm ended all xtb reads
    float wfv = Wf_w[col];
    #pragma unroll
    for (int mt = 0; mt < 2; ++mt)
        #pragma unroll
        for (int e = 0; e < 4; ++e) {
            float p = sreg4[mt][e] * wfv;
            p += __shfl_xor(p, 1);
            p += __shfl_xor(p, 2);
            p += __shfl_xor(p, 4);
            p += __shfl_xor(p, 8);
            if (l15 == 0) yp[(mt * 16 + quad * 4 + e) * 8 + wv] = p;
        }
    __syncthreads();
    if (tid < BROWS) {
        const float* r8 = yp + tid * 8;
        float r = ((r8[0] + r8[1]) + (r8[2] + r8[3])) +
                  ((r8[4] + r8[5]) + (r8[6] + r8[7])) + Wf_b[0];
        y[(size_t)blk * BROWS + tid] = r;
    }
}

extern "C" void kernel_launch(void* const* d_in, const int* in_sizes, int n_in,
                              void* d_out, int out_size, void* d_ws, size_t ws_size,
                              hipStream_t stream) {
    const float* x     = (const float*)d_in[0];
    const float* t     = (const float*)d_in[1];
    const float* Sw_w  = (const float*)d_in[2];
    const float* Sw_b  = (const float*)d_in[3];
    const float* Uz_w  = (const float*)d_in[4];
    const float* Uz_b  = (const float*)d_in[5];
    const float* Wsz_w = (const float*)d_in[6];
    const float* Wsz_b = (const float*)d_in[7];
    const float* Ug_w  = (const float*)d_in[8];
    const float* Ug_b  = (const float*)d_in[9];
    const float* Wsg_w = (const float*)d_in[10];
    const float* Wsg_b = (const float*)d_in[11];
    const float* Ur_w  = (const float*)d_in[12];
    const float* Ur_b  = (const float*)d_in[13];
    const float* Wsr_w = (const float*)d_in[14];
    const float* Wsr_b = (const float*)d_in[15];
    const float* Uh_w  = (const float*)d_in[16];
    const float* Uh_b  = (const float*)d_in[17];
    const float* Wsh_w = (const float*)d_in[18];
    const float* Wsh_b = (const float*)d_in[19];
    const float* Wf_w  = (const float*)d_in[20];
    const float* Wf_b  = (const float*)d_in[21];
    const int*   nl    = (const int*)d_in[22];

    unsigned short* wbuf = (unsigned short*)d_ws;
    float* y = (float*)d_out;
    const int B = in_sizes[0] / XD;

    prep_kernel<<<dim3((NMAT * 4096 + 255) / 256), dim3(256), 0, stream>>>(
        Sw_w, Uz_w, Ug_w, Ur_w, Uh_w, Wsz_w, Wsg_w, Wsr_w, Wsh_w, wbuf);

    dgm_main<<<dim3(B / BROWS), dim3(512), 0, stream>>>(
        x, t, wbuf, Sw_b, Uz_b, Ug_b, Ur_b, Uh_b,
        Wsz_b, Wsg_b, Wsr_b, Wsh_b, Wf_w, Wf_b, nl, y);
}

// Round 7
// 378.344 us; speedup vs baseline: 1.2483x; 1.2483x over previous
//
#include <hip/hip_runtime.h>

// DGMNet fused kernel for MI355X (gfx950) — round 7.
// R2-R6 mechanism (now solid): the RA's register budget = VGPR pool divided by
// the LDS-implied max waves/EU tier; excess live state spills. Hints ignored.
// R6 failed because a separate dead LDS pad object was deleted (LDS fell to
// 16KB -> 64-reg budget -> 320MB spill). R7:
//  - ONE __shared__ array of 64KB; xtb/sb are runtime-offset views inside it.
//    A partially-used single object can't be shrunk -> LDS stays 65536 ->
//    2 blocks/CU @512thr -> 4 waves/EU -> 128-reg RA budget.
//  - u-projections repacked to bf16 pairs (16 regs, was 32 fp32) so live
//    state (~125) fits the 128 budget. tp/gp/sreg stay fp32.
//  - Everything else as R6 (bias folded into MFMA C-init, fp32 epilogues).

typedef __attribute__((ext_vector_type(8))) short bf16x8;
typedef __attribute__((ext_vector_type(4))) float f32x4;
typedef __attribute__((ext_vector_type(4))) unsigned int u32x4;
typedef __attribute__((ext_vector_type(2))) unsigned int u32x2;

#define HID 128
#define XD 100
#define BROWS 32
#define NMAT 9
#define MATS 16384   // ushorts per 128x128 matrix

// ---------- bf16 helpers (RNE) ----------
__device__ __forceinline__ unsigned short f2bf(float f) {
    unsigned u = __float_as_uint(f);
    return (unsigned short)((u + 0x7FFFu + ((u >> 16) & 1u)) >> 16);
}
__device__ __forceinline__ unsigned pack2(float lo, float hi) {
    unsigned ul = __float_as_uint(lo), uh = __float_as_uint(hi);
    unsigned bl = (ul + 0x7FFFu + ((ul >> 16) & 1u)) >> 16;
    unsigned bh = (uh + 0x7FFFu + ((uh >> 16) & 1u)) & 0xFFFF0000u;
    return bl | bh;
}
__device__ __forceinline__ float bf_lo(unsigned p) { return __uint_as_float(p << 16); }
__device__ __forceinline__ float bf_hi(unsigned p) { return __uint_as_float(p & 0xFFFF0000u); }

__device__ __forceinline__ float fast_tanh(float x) {
    float e = __expf(2.0f * x);
    return 1.0f - 2.0f * __builtin_amdgcn_rcpf(e + 1.0f);
}
__device__ __forceinline__ float one_m_tanh(float x) {   // 1 - tanh(x)
    float e = __expf(2.0f * x);
    return 2.0f * __builtin_amdgcn_rcpf(e + 1.0f);
}

// ---------- prep: fp32 [K][128] -> bf16 fragment order (coalesced reads) ----
// mats: 0 Sw 1 Uz 2 Ug 3 Ur 4 Uh (K=101, pad to 128) | 5 Wsz 6 Wsg 7 Wsr 8 Wsh
// frag layout: ((ks*8+nt)*64+lane)*8+b <-> W[k=ks*32+(lane>>4)*8+b][n=nt*16+(lane&15)]
__global__ void prep_kernel(const float* __restrict__ Sw, const float* __restrict__ Uz,
                            const float* __restrict__ Ug, const float* __restrict__ Ur,
                            const float* __restrict__ Uh, const float* __restrict__ Wsz,
                            const float* __restrict__ Wsg, const float* __restrict__ Wsr,
                            const float* __restrict__ Wsh, unsigned short* __restrict__ out) {
    int g = blockIdx.x * blockDim.x + threadIdx.x;
    if (g >= NMAT * 4096) return;           // 128 k x 32 n-quads per matrix
    int m = g >> 12, r = g & 4095;
    int k = r >> 5, n4 = (r & 31) * 4;
    const float* src; int kmax;
    switch (m) {
        case 0: src = Sw;  kmax = 101; break;
        case 1: src = Uz;  kmax = 101; break;
        case 2: src = Ug;  kmax = 101; break;
        case 3: src = Ur;  kmax = 101; break;
        case 4: src = Uh;  kmax = 101; break;
        case 5: src = Wsz; kmax = 128; break;
        case 6: src = Wsg; kmax = 128; break;
        case 7: src = Wsr; kmax = 128; break;
        default: src = Wsh; kmax = 128; break;
    }
    f32x4 v = (f32x4){0.f, 0.f, 0.f, 0.f};
    if (k < kmax) v = *(const f32x4*)(src + k * HID + n4);
    int ks = k >> 5, b = k & 7, lq = ((k >> 3) & 3) << 4;
    int nt = n4 >> 4;
    size_t mb = (size_t)m * MATS;
    #pragma unroll
    for (int i = 0; i < 4; ++i) {
        int lane = lq | ((n4 + i) & 15);
        out[mb + (size_t)((ks * 8 + nt) * 64 + lane) * 8 + b] = f2bf(v[i]);
    }
}

// ---------- GEMM: A (LDS, frag order, 32 rows x 128 k) x B (regs, 1 n-tile) ----------
// acc must be pre-initialized by the caller (C-operand carries u/bias).
__device__ __forceinline__ void gemm32(const unsigned short* __restrict__ A,
                                       const bf16x8 (&B)[4], int lane,
                                       f32x4 (&acc)[2]) {
    #pragma unroll
    for (int ks = 0; ks < 4; ++ks) {
        #pragma unroll
        for (int mt = 0; mt < 2; ++mt) {
            bf16x8 a = *(const bf16x8*)(A + mt * 2048 + ks * 512 + lane * 8);
            acc[mt] = __builtin_amdgcn_mfma_f32_16x16x32_bf16(a, B[ks], acc[mt], 0, 0, 0);
        }
    }
}

__device__ __forceinline__ void loadB(const unsigned short* __restrict__ wbuf, int mat,
                                      int nt, int lane, bf16x8 (&B)[4]) {
    #pragma unroll
    for (int ks = 0; ks < 4; ++ks)
        B[ks] = *(const bf16x8*)(wbuf + (size_t)mat * MATS +
                                 ((size_t)((ks * 8 + nt) * 64 + lane)) * 8);
}

// ---------- main ----------
__global__ __launch_bounds__(512, 4)
void dgm_main(const float* __restrict__ x, const float* __restrict__ tptr,
              const unsigned short* __restrict__ wbuf,
              const float* __restrict__ Sw_b, const float* __restrict__ Uz_b,
              const float* __restrict__ Ug_b, const float* __restrict__ Ur_b,
              const float* __restrict__ Uh_b,
              const float* __restrict__ Wsz_b, const float* __restrict__ Wsg_b,
              const float* __restrict__ Wsr_b, const float* __restrict__ Wsh_b,
              const float* __restrict__ Wf_w, const float* __restrict__ Wf_b,
              const int* __restrict__ nlayers, float* __restrict__ y) {
    // ONE 64KB LDS object. xtb = [0,4096) ushorts, sb = [4096,8192).
    // The tail is deliberately untouched: it pins the LDS-occupancy tier at
    // 2 blocks/CU (512 thr) = 4 waves/EU, so the RA budget is 128 regs
    // (R2-R6: RA budget = pool / LDS-implied max waves; spills the excess).
    __shared__ unsigned short lds[32768];
    unsigned short* xtb = lds;           // A-frag order: xt, later S*R (8KB)
    unsigned short* sb  = lds + 4096;    // A-frag order: S (8KB)

    const int tid = threadIdx.x;
    const int wv = tid >> 6, lane = tid & 63;
    const int quad = lane >> 4, l15 = lane & 15;
    const int blk = blockIdx.x;
    const int lcount = nlayers[0] - 1;
    const int nt = wv;                       // one 16-col n-tile per wave

    const int col = nt * 16 + l15;
    const int sc = (col >> 5) * 512 + ((col >> 3) & 3) * 128 + (col & 7) + quad * 32;

    // ---- zero the k>=96 pad frags of xtb (frag ks==3), then fill xt ----
    {
        int mt = tid >> 8;
        ((unsigned*)xtb)[mt * 1024 + 768 + (tid & 255)] = 0u;
    }
    __syncthreads();

    {
        const float* xsrc = x + (size_t)blk * BROWS * XD;
        for (int i = tid; i < BROWS * (XD / 4); i += 512) {     // 800 float4s
            int row = i / 25, c4 = i % 25, k0 = c4 * 4;
            f32x4 v = *(const f32x4*)(xsrc + row * XD + k0);
            int idx = (row >> 4) * 2048 + (k0 >> 5) * 512 + ((k0 >> 3) & 3) * 128 +
                      (row & 15) * 8 + (k0 & 7);
            *(u32x2*)(xtb + idx) = (u32x2){pack2(v[0], v[1]), pack2(v[2], v[3])};
        }
        if (tid < BROWS) {                                      // t column, k=100
            int idx = (tid >> 4) * 2048 + 3 * 512 + (tid & 15) * 8 + 4;
            xtb[idx] = f2bf(tptr[(size_t)blk * BROWS + tid]);
        }
    }
    __syncthreads();

    f32x4 acc[2];
    f32x4 sreg4[2];       // S (fp32, C-layout)
    unsigned u2[4][2][2]; // pre-biased projections, packed bf16: 0 uz 1 ug 2 ur 3 uh
    bf16x8 Bcur[4], Bnxt[4];

    // ---- projection phase: Sw, then Uz/Ug/Ur/Uh (bias folded into C-init) ----
    loadB(wbuf, 0, nt, lane, Bcur);
    {
        float bv = Sw_b[col];
        loadB(wbuf, 1, nt, lane, Bnxt);   // prefetch Uz
        acc[0] = (f32x4){bv, bv, bv, bv};
        acc[1] = acc[0];
        gemm32(xtb, Bcur, lane, acc);
        #pragma unroll
        for (int mt = 0; mt < 2; ++mt) {
            f32x4 s;
            s[0] = fast_tanh(acc[mt][0]);
            s[1] = fast_tanh(acc[mt][1]);
            s[2] = fast_tanh(acc[mt][2]);
            s[3] = fast_tanh(acc[mt][3]);
            sreg4[mt] = s;
            unsigned p01 = pack2(s[0], s[1]), p23 = pack2(s[2], s[3]);
            int base = mt * 2048 + sc;
            sb[base + 0]  = (unsigned short)p01;
            sb[base + 8]  = (unsigned short)(p01 >> 16);
            sb[base + 16] = (unsigned short)p23;
            sb[base + 24] = (unsigned short)(p23 >> 16);
        }
    }
    {
        const float* ubias[4] = {Uz_b, Ug_b, Ur_b, Uh_b};
        #pragma unroll
        for (int mi = 0; mi < 4; ++mi) {
            #pragma unroll
            for (int ks = 0; ks < 4; ++ks)
                Bcur[ks] = Bnxt[ks];
            if (mi < 3) loadB(wbuf, mi + 2, nt, lane, Bnxt);
            float bv = ubias[mi][col];
            acc[0] = (f32x4){bv, bv, bv, bv};
            acc[1] = acc[0];
            gemm32(xtb, Bcur, lane, acc);    // acc = xt@U + b  (pre-biased u)
            u2[mi][0][0] = pack2(acc[0][0], acc[0][1]);
            u2[mi][0][1] = pack2(acc[0][2], acc[0][3]);
            u2[mi][1][0] = pack2(acc[1][0], acc[1][1]);
            u2[mi][1][1] = pack2(acc[1][2], acc[1][3]);
        }
    }
    __syncthreads();   // S1 visible to all waves

    // ---- persistent layer weights (B-fragments, this wave's n-tile) ----
    bf16x8 Wz[4], Wg[4], Wr[4], Wh[4];
    loadB(wbuf, 5, nt, lane, Wz);
    loadB(wbuf, 6, nt, lane, Wg);
    loadB(wbuf, 7, nt, lane, Wr);
    loadB(wbuf, 8, nt, lane, Wh);

    f32x4 tp4[2];   // Z*S (fp32)
    f32x4 gp4[2];   // 1-G (fp32)

    // ---- recurrent layers: R -> Z -> G -> H ----
    for (int l = 0; l < lcount; ++l) {
        // R = tanh(ur + S@Wsr); write S*R into xtb
        #pragma unroll
        for (int mt = 0; mt < 2; ++mt)
            acc[mt] = (f32x4){bf_lo(u2[2][mt][0]), bf_hi(u2[2][mt][0]),
                              bf_lo(u2[2][mt][1]), bf_hi(u2[2][mt][1])};
        gemm32(sb, Wr, lane, acc);
        #pragma unroll
        for (int mt = 0; mt < 2; ++mt) {
            float q0 = sreg4[mt][0] * fast_tanh(acc[mt][0]);
            float q1 = sreg4[mt][1] * fast_tanh(acc[mt][1]);
            float q2 = sreg4[mt][2] * fast_tanh(acc[mt][2]);
            float q3 = sreg4[mt][3] * fast_tanh(acc[mt][3]);
            unsigned q01 = pack2(q0, q1), q23 = pack2(q2, q3);
            int base = mt * 2048 + sc;
            xtb[base + 0]  = (unsigned short)q01;
            xtb[base + 8]  = (unsigned short)(q01 >> 16);
            xtb[base + 16] = (unsigned short)q23;
            xtb[base + 24] = (unsigned short)(q23 >> 16);
        }
        __syncthreads();   // S*R visible

        // Z = tanh(uz + S@Wsz); tp = Z*S
        #pragma unroll
        for (int mt = 0; mt < 2; ++mt)
            acc[mt] = (f32x4){bf_lo(u2[0][mt][0]), bf_hi(u2[0][mt][0]),
                              bf_lo(u2[0][mt][1]), bf_hi(u2[0][mt][1])};
        gemm32(sb, Wz, lane, acc);
        #pragma unroll
        for (int mt = 0; mt < 2; ++mt) {
            tp4[mt][0] = fast_tanh(acc[mt][0]) * sreg4[mt][0];
            tp4[mt][1] = fast_tanh(acc[mt][1]) * sreg4[mt][1];
            tp4[mt][2] = fast_tanh(acc[mt][2]) * sreg4[mt][2];
            tp4[mt][3] = fast_tanh(acc[mt][3]) * sreg4[mt][3];
        }

        // 1-G = 2/(exp(2*(ug + S@Wsg))+1)
        #pragma unroll
        for (int mt = 0; mt < 2; ++mt)
            acc[mt] = (f32x4){bf_lo(u2[1][mt][0]), bf_hi(u2[1][mt][0]),
                              bf_lo(u2[1][mt][1]), bf_hi(u2[1][mt][1])};
        gemm32(sb, Wg, lane, acc);
        #pragma unroll
        for (int mt = 0; mt < 2; ++mt) {
            gp4[mt][0] = one_m_tanh(acc[mt][0]);
            gp4[mt][1] = one_m_tanh(acc[mt][1]);
            gp4[mt][2] = one_m_tanh(acc[mt][2]);
            gp4[mt][3] = one_m_tanh(acc[mt][3]);
        }

        // H = uh + (S*R)@Wsh ; out = (1-G)*H + Z*S
        #pragma unroll
        for (int mt = 0; mt < 2; ++mt)
            acc[mt] = (f32x4){bf_lo(u2[3][mt][0]), bf_hi(u2[3][mt][0]),
                              bf_lo(u2[3][mt][1]), bf_hi(u2[3][mt][1])};
        gemm32(xtb, Wh, lane, acc);
        __syncthreads();   // all waves done reading sb/xtb for this layer
        bool lastl = (l == lcount - 1);
        #pragma unroll
        for (int mt = 0; mt < 2; ++mt) {
            f32x4 o;
            o[0] = gp4[mt][0] * acc[mt][0] + tp4[mt][0];
            o[1] = gp4[mt][1] * acc[mt][1] + tp4[mt][1];
            o[2] = gp4[mt][2] * acc[mt][2] + tp4[mt][2];
            o[3] = gp4[mt][3] * acc[mt][3] + tp4[mt][3];
            sreg4[mt] = o;
            if (!lastl) {
                unsigned p01 = pack2(o[0], o[1]), p23 = pack2(o[2], o[3]);
                int base = mt * 2048 + sc;
                sb[base + 0]  = (unsigned short)p01;
                sb[base + 8]  = (unsigned short)(p01 >> 16);
                sb[base + 16] = (unsigned short)p23;
                sb[base + 24] = (unsigned short)(p23 >> 16);
            }
        }
        if (!lastl) __syncthreads();   // new S visible for next layer
    }

    // ---- final: y = out @ Wf + Wf_b (per-wave partials, combine via LDS) ----
    float* yp = (float*)xtb;   // safe: barrier after H-gemm ended all xtb reads
    float wfv = Wf_w[col];
    #pragma unroll
    for (int mt = 0; mt < 2; ++mt)
        #pragma unroll
        for (int e = 0; e < 4; ++e) {
            float p = sreg4[mt][e] * wfv;
            p += __shfl_xor(p, 1);
            p += __shfl_xor(p, 2);
            p += __shfl_xor(p, 4);
            p += __shfl_xor(p, 8);
            if (l15 == 0) yp[(mt * 16 + quad * 4 + e) * 8 + wv] = p;
        }
    __syncthreads();
    if (tid < BROWS) {
        const float* r8 = yp + tid * 8;
        float r = ((r8[0] + r8[1]) + (r8[2] + r8[3])) +
                  ((r8[4] + r8[5]) + (r8[6] + r8[7])) + Wf_b[0];
        y[(size_t)blk * BROWS + tid] = r;
    }
}

extern "C" void kernel_launch(void* const* d_in, const int* in_sizes, int n_in,
                              void* d_out, int out_size, void* d_ws, size_t ws_size,
                              hipStream_t stream) {
    const float* x     = (const float*)d_in[0];
    const float* t     = (const float*)d_in[1];
    const float* Sw_w  = (const float*)d_in[2];
    const float* Sw_b  = (const float*)d_in[3];
    const float* Uz_w  = (const float*)d_in[4];
    const float* Uz_b  = (const float*)d_in[5];
    const float* Wsz_w = (const float*)d_in[6];
    const float* Wsz_b = (const float*)d_in[7];
    const float* Ug_w  = (const float*)d_in[8];
    const float* Ug_b  = (const float*)d_in[9];
    const float* Wsg_w = (const float*)d_in[10];
    const float* Wsg_b = (const float*)d_in[11];
    const float* Ur_w  = (const float*)d_in[12];
    const float* Ur_b  = (const float*)d_in[13];
    const float* Wsr_w = (const float*)d_in[14];
    const float* Wsr_b = (const float*)d_in[15];
    const float* Uh_w  = (const float*)d_in[16];
    const float* Uh_b  = (const float*)d_in[17];
    const float* Wsh_w = (const float*)d_in[18];
    const float* Wsh_b = (const float*)d_in[19];
    const float* Wf_w  = (const float*)d_in[20];
    const float* Wf_b  = (const float*)d_in[21];
    const int*   nl    = (const int*)d_in[22];

    unsigned short* wbuf = (unsigned short*)d_ws;
    float* y = (float*)d_out;
    const int B = in_sizes[0] / XD;

    prep_kernel<<<dim3((NMAT * 4096 + 255) / 256), dim3(256), 0, stream>>>(
        Sw_w, Uz_w, Ug_w, Ur_w, Uh_w, Wsz_w, Wsg_w, Wsr_w, Wsh_w, wbuf);

    dgm_main<<<dim3(B / BROWS), dim3(512), 0, stream>>>(
        x, t, wbuf, Sw_b, Uz_b, Ug_b, Ur_b, Uh_b,
        Wsz_b, Wsg_b, Wsr_b, Wsh_b, Wf_w, Wf_b, nl, y);
}